// Round 6
// baseline (507.214 us; speedup 1.0000x reference)
//
#include <hip/hip_runtime.h>
#include <hip/hip_bf16.h>
#include <math.h>

#define B_   2
#define S_   2048
#define HID  2048
#define NH   16
#define HD   128

typedef __bf16 bf16_t;
typedef __bf16 bf16x4 __attribute__((ext_vector_type(4)));
typedef __bf16 bf16x8 __attribute__((ext_vector_type(8)));
typedef float  f32x4  __attribute__((ext_vector_type(4)));
typedef unsigned int u32x4 __attribute__((ext_vector_type(4)));

__device__ __forceinline__ f32x4 mfma16(bf16x8 a, bf16x8 b, f32x4 c) {
    return __builtin_amdgcn_mfma_f32_16x16x32_bf16(a, b, c, 0, 0, 0);
}

__device__ __forceinline__ void gl2lds16(const void* g, void* l) {
    __builtin_amdgcn_global_load_lds((__attribute__((address_space(1))) void*)(g),
                                     (__attribute__((address_space(3))) void*)(l),
                                     16, 0, 0);
}

// pack two floats into one u32 of 2 bf16 (lo = a, hi = b)
__device__ __forceinline__ unsigned int pkbf(float a, float b) {
    unsigned short ua = __builtin_bit_cast(unsigned short, (bf16_t)a);
    unsigned short ub = __builtin_bit_cast(unsigned short, (bf16_t)b);
    return (unsigned int)ua | ((unsigned int)ub << 16);
}

// ---------------------------------------------------------------------------
// fp32 -> bf16 conversion of hs + 4 weights (float4 in, bf16x4 out).
// ---------------------------------------------------------------------------
__global__ void convert_bf16(const float* __restrict__ s0, const float* __restrict__ s1,
                             const float* __restrict__ s2, const float* __restrict__ s3,
                             const float* __restrict__ s4,
                             bf16_t* __restrict__ d0, bf16_t* __restrict__ d1,
                             bf16_t* __restrict__ d2, bf16_t* __restrict__ d3,
                             bf16_t* __restrict__ d4)
{
    const size_t stride = (size_t)gridDim.x * blockDim.x;
    for (size_t i = (size_t)blockIdx.x * blockDim.x + threadIdx.x; i < 4325376; i += stride) {
        const float* s; bf16_t* d; size_t off;
        if (i < 2097152)      { s = s0; d = d0; off = i; }
        else if (i < 3145728) { s = s1; d = d1; off = i - 2097152; }
        else if (i < 3211264) { s = s2; d = d2; off = i - 3145728; }
        else if (i < 3276800) { s = s3; d = d3; off = i - 3211264; }
        else                  { s = s4; d = d4; off = i - 3276800; }
        float4 v = ((const float4*)s)[off];
        bf16x4 o;
        o[0] = (bf16_t)v.x; o[1] = (bf16_t)v.y; o[2] = (bf16_t)v.z; o[3] = (bf16_t)v.w;
        ((bf16x4*)d)[off] = o;
    }
}

// ---------------------------------------------------------------------------
// broadcast compact bf16 K/V [b][s][128] -> fp32 key/value_states [b][16][s][128].
// ---------------------------------------------------------------------------
__global__ void broadcast_kv(const bf16_t* __restrict__ k_ws, const bf16_t* __restrict__ v_ws,
                             float* __restrict__ keyo, float* __restrict__ valo)
{
    const size_t stride = (size_t)gridDim.x * blockDim.x;
    for (size_t i = (size_t)blockIdx.x * blockDim.x + threadIdx.x; i < 4194304; i += stride) {
        int which = i >= 2097152;
        size_t f = which ? i - 2097152 : i;
        size_t e = f * 4;                         // < 8388608
        int d = (int)(e & 127);
        size_t s = (e >> 7) & 2047;
        size_t b = e >> 22;                       // 0 or 1
        const bf16_t* src = (which ? v_ws : k_ws) + (b * S_ + s) * HD + d;
        bf16x4 kv = *(const bf16x4*)src;
        float4 o;
        o.x = (float)kv[0]; o.y = (float)kv[1]; o.z = (float)kv[2]; o.w = (float)kv[3];
        *(float4*)((which ? valo : keyo) + e) = o;
    }
}

// ---------------------------------------------------------------------------
// NT GEMM, 128x128 tile, BK=32, 4 waves (2x2 of 64x64), mfma 16x16x32 bf16.
// MODE 0: C = Xb @ [Wq;Wk;Wv]b^T (N=2304): bn<16 -> qb; bn==16 -> k_ws;
//         bn==17 -> v_ws + vt_ws.   MODE 1: C = O @ Wo^T -> fp32 out.
// ---------------------------------------------------------------------------
template <int MODE>
__global__ __launch_bounds__(256, 2)
void gemm_nt(const bf16_t* __restrict__ A,  const bf16_t* __restrict__ B0,
             const bf16_t* __restrict__ B1, const bf16_t* __restrict__ B2,
             bf16_t* __restrict__ q_ws, bf16_t* __restrict__ k_ws,
             bf16_t* __restrict__ v_ws, bf16_t* __restrict__ vt_ws,
             float* __restrict__ outf)
{
    __shared__ __align__(16) ushort sA[128 * 32];
    __shared__ __align__(16) ushort sB[128 * 32];

    const int tid  = threadIdx.x;
    const int lane = tid & 63;
    const int wave = tid >> 6;
    const int quad = lane >> 4;
    const int l16  = lane & 15;
    const int bn = blockIdx.x, bm = blockIdx.y;
    const int wm = (wave & 1) * 64;
    const int wn = (wave >> 1) * 64;

    const bf16_t* Bbase;
    if (MODE == 0) Bbase = (bn < 16) ? (B0 + (size_t)bn * 128 * HID) : (bn == 16 ? B1 : B2);
    else           Bbase = B0 + (size_t)bn * 128 * HID;
    const bf16_t* Abase = A + (size_t)bm * 128 * HID;

    const int c0 = tid, c1 = tid + 256;
    const int r0 = c0 >> 2, o0 = (c0 & 3) * 8;
    const int r1 = c1 >> 2, o1 = (c1 & 3) * 8;

    f32x4 acc[4][4] = {};

    for (int kt = 0; kt < HID / 32; ++kt) {
        const int ko = kt * 32;
        gl2lds16(Abase + (size_t)r0 * HID + ko + o0, sA + c0 * 8);
        gl2lds16(Abase + (size_t)r1 * HID + ko + o1, sA + c1 * 8);
        gl2lds16(Bbase + (size_t)r0 * HID + ko + o0, sB + c0 * 8);
        gl2lds16(Bbase + (size_t)r1 * HID + ko + o1, sB + c1 * 8);
        __syncthreads();

        bf16x8 af[4], bfr[4];
        for (int mt = 0; mt < 4; ++mt)
            af[mt] = *(const bf16x8*)(sA + (wm + mt * 16 + l16) * 32 + quad * 8);
        for (int nt = 0; nt < 4; ++nt)
            bfr[nt] = *(const bf16x8*)(sB + (wn + nt * 16 + l16) * 32 + quad * 8);
        for (int mt = 0; mt < 4; ++mt)
            for (int nt = 0; nt < 4; ++nt)
                acc[mt][nt] = mfma16(af[mt], bfr[nt], acc[mt][nt]);
        __syncthreads();
    }

    for (int mt = 0; mt < 4; ++mt) {
        for (int nt = 0; nt < 4; ++nt) {
            for (int j = 0; j < 4; ++j) {
                float v = acc[mt][nt][j];
                int row = bm * 128 + wm + mt * 16 + quad * 4 + j;
                int col = wn + nt * 16 + l16;
                if (MODE == 1) {
                    outf[(size_t)row * HID + bn * 128 + col] = v;
                } else {
                    bf16_t bv = (bf16_t)v;
                    if (bn < 16) {
                        q_ws[(size_t)row * HID + bn * 128 + col] = bv;
                    } else {
                        int b = row >> 11, s = row & 2047, d = col;
                        if (bn == 16) {
                            k_ws[((size_t)b * S_ + s) * HD + d] = bv;
                        } else {
                            v_ws[((size_t)b * S_ + s) * HD + d] = bv;
                            vt_ws[((size_t)b * HD + d) * S_ + s] = bv;
                        }
                    }
                }
            }
        }
    }
}

// ---------------------------------------------------------------------------
// Flash-style MQA attention, round 6: ZERO-LDS / ZERO-BARRIER.
// K (512 KB/batch) and V^T (512 KB/batch) are L2-resident and their MFMA
// B-fragments are 16B-contiguous per lane in GLOBAL layout -> load fragments
// straight from global (L2 hit), no staging, no __syncthreads at all.
// The compiler is free to software-pipeline fragment loads across the whole
// iteration (no fences, no LDS aliasing). Swapped QK^T (S^T = mfma(K,Q)) with
// in-register softmax + lane-local shuffle routing of P into PV A-frags
// (verified round 5, absmax 0.03125). exp2 domain + deferred-max (THR=8).
// Block = 256 thr (4 independent waves, 32 q-rows each); grid (16,32).
// ---------------------------------------------------------------------------
__global__ __launch_bounds__(256, 2)
void attn_kernel(const bf16_t* __restrict__ Qw, const bf16_t* __restrict__ Kc,
                 const bf16_t* __restrict__ Vt, const float* __restrict__ mask,
                 bf16_t* __restrict__ Ow)
{
    const int tid  = threadIdx.x;
    const int lane = tid & 63;
    const int wave = tid >> 6;     // 0..3
    const int quad = lane >> 4;
    const int l16  = lane & 15;
    const int qt = blockIdx.x;     // 0..15 (128-row q-tiles)
    const int bh = blockIdx.y;     // 0..31
    const int b = bh >> 4, h = bh & 15;

    const bf16_t* kg = Kc + (size_t)b * S_ * HD;
    const bf16_t* vg = Vt + (size_t)b * HD * S_;
    const float*  mg = mask + (size_t)b * S_;

    // ---- Q fragments (B-operand: row=q=l16, k-elems=d): global -> regs ----
    bf16x8 qf[2][4];
    {
        const bf16_t* qg = Qw + ((size_t)(b * S_ + qt * 128 + wave * 32)) * HID + h * HD;
#pragma unroll
        for (int mt = 0; mt < 2; ++mt)
#pragma unroll
            for (int kk = 0; kk < 4; ++kk)
                qf[mt][kk] = *(const bf16x8*)(qg + (size_t)(mt * 16 + l16) * HID + kk * 32 + quad * 8);
    }

    f32x4 oa[2][8] = {};
    float mrow[2] = { -INFINITY, -INFINITY };
    float lrow[2] = { 0.f, 0.f };

    const float scale2 = 0.08838834764831845f * 1.4426950408889634f;  // /sqrt(128)*log2(e)
    const float NEGF   = -3.4028234663852886e38f;
    const float LOG2E  = 1.4426950408889634f;

    for (int kt = 0; kt < S_ / 64; ++kt) {
        // ---- S^T = (K Q^T): kf straight from global (L2); sa: row=k_local, col=q ----
        // kf row = k (= kt*64 + nt*16 + l16), elems = 8 d at (kk*32 + quad*8)
        f32x4 sa[2][4] = {};
        const bf16_t* kbase = kg + (size_t)kt * 64 * HD;
#pragma unroll
        for (int kk = 0; kk < 4; ++kk)
#pragma unroll
            for (int nt = 0; nt < 4; ++nt) {
                bf16x8 kf = *(const bf16x8*)(kbase + (size_t)(nt * 16 + l16) * HD + kk * 32 + quad * 8);
#pragma unroll
                for (int mt = 0; mt < 2; ++mt)
                    sa[mt][nt] = mfma16(kf, qf[mt][kk], sa[mt][nt]);
            }
        // scale + mask (mask indexed by k = nt*16 + quad*4 + j)
#pragma unroll
        for (int nt = 0; nt < 4; ++nt) {
            f32x4 m4 = *(const f32x4*)(mg + kt * 64 + nt * 16 + quad * 4);
#pragma unroll
            for (int j = 0; j < 4; ++j) {
                float madd = (1.0f - m4[j]) * NEGF * LOG2E;
#pragma unroll
                for (int mt = 0; mt < 2; ++mt)
                    sa[mt][nt][j] = sa[mt][nt][j] * scale2 + madd;
            }
        }

        // ---- in-register online softmax: lane owns q=l16 (16 k-vals in-lane) ----
        float rm[2];
#pragma unroll
        for (int mt = 0; mt < 2; ++mt) {
            float m = sa[mt][0][0];
#pragma unroll
            for (int nt = 0; nt < 4; ++nt)
#pragma unroll
                for (int j = 0; j < 4; ++j)
                    m = fmaxf(m, sa[mt][nt][j]);
            m = fmaxf(m, __shfl_xor(m, 16));
            m = fmaxf(m, __shfl_xor(m, 32));
            rm[mt] = m;
        }
        bool need = (rm[0] > mrow[0] + 8.0f) || (rm[1] > mrow[1] + 8.0f);
        if (__any((int)need)) {
#pragma unroll
            for (int mt = 0; mt < 2; ++mt) {
                float mnew  = fmaxf(mrow[mt], rm[mt]);
                float alpha = exp2f(mrow[mt] - mnew);
                mrow[mt] = mnew;
                lrow[mt] *= alpha;
#pragma unroll
                for (int j = 0; j < 4; ++j) {
                    float aj = __shfl(alpha, (lane & 48) | (quad * 4 + j));
#pragma unroll
                    for (int nt = 0; nt < 8; ++nt) oa[mt][nt][j] *= aj;
                }
            }
        }
        // p = exp2(s - m), packed to bf16 pairs; row-sum -> lrow
        unsigned int g[2][4][2];
#pragma unroll
        for (int mt = 0; mt < 2; ++mt) {
            float rs = 0.f;
#pragma unroll
            for (int nt = 0; nt < 4; ++nt) {
                float p0 = exp2f(sa[mt][nt][0] - mrow[mt]);
                float p1 = exp2f(sa[mt][nt][1] - mrow[mt]);
                float p2 = exp2f(sa[mt][nt][2] - mrow[mt]);
                float p3 = exp2f(sa[mt][nt][3] - mrow[mt]);
                rs += (p0 + p1) + (p2 + p3);
                g[mt][nt][0] = pkbf(p0, p1);
                g[mt][nt][1] = pkbf(p2, p3);
            }
            rs += __shfl_xor(rs, 16);
            rs += __shfl_xor(rs, 32);
            lrow[mt] += rs;
        }

        // ---- build PV A-frags by lane-local quad routing (same l16 column) ----
        bf16x8 pf[2][2];
        {
            const int sl = ((quad & 1) << 5) + l16;   // src for e0..3 (quad 0 or 2)
            const int sh = sl + 16;                   // src for e4..7 (quad 1 or 3)
            const bool hi = (quad & 2) != 0;          // nt-select: 2kk or 2kk+1
#pragma unroll
            for (int kk = 0; kk < 2; ++kk)
#pragma unroll
                for (int mt = 0; mt < 2; ++mt) {
                    unsigned int a0 = __shfl(g[mt][2 * kk][0], sl);
                    unsigned int a1 = __shfl(g[mt][2 * kk][1], sl);
                    unsigned int b0 = __shfl(g[mt][2 * kk + 1][0], sl);
                    unsigned int b1 = __shfl(g[mt][2 * kk + 1][1], sl);
                    unsigned int c0 = __shfl(g[mt][2 * kk][0], sh);
                    unsigned int c1 = __shfl(g[mt][2 * kk][1], sh);
                    unsigned int d0 = __shfl(g[mt][2 * kk + 1][0], sh);
                    unsigned int d1 = __shfl(g[mt][2 * kk + 1][1], sh);
                    u32x4 w;
                    w[0] = hi ? b0 : a0;
                    w[1] = hi ? b1 : a1;
                    w[2] = hi ? d0 : c0;
                    w[3] = hi ? d1 : c1;
                    pf[mt][kk] = __builtin_bit_cast(bf16x8, w);
                }
        }

        // ---- O += P V: vf straight from global V^T (L2) ----
        // vf row = d (= nt*16 + l16), elems = 8 k at kt*64 + (kk*32 + quad*8)
#pragma unroll
        for (int kk = 0; kk < 2; ++kk)
#pragma unroll
            for (int nt = 0; nt < 8; ++nt) {
                bf16x8 vf = *(const bf16x8*)(vg + (size_t)(nt * 16 + l16) * S_ + kt * 64 + kk * 32 + quad * 8);
#pragma unroll
                for (int mt = 0; mt < 2; ++mt)
                    oa[mt][nt] = mfma16(pf[mt][kk], vf, oa[mt][nt]);
            }
    }

    // ---- epilogue: O /= l (l at lane l16=row; fetch via shfl), write ----
#pragma unroll
    for (int mt = 0; mt < 2; ++mt)
#pragma unroll
        for (int j = 0; j < 4; ++j) {
            float lv = __shfl(lrow[mt], (lane & 48) | (quad * 4 + j));
            float inv = 1.0f / lv;
            int s = qt * 128 + wave * 32 + mt * 16 + quad * 4 + j;
#pragma unroll
            for (int nt = 0; nt < 8; ++nt) {
                int d = nt * 16 + l16;
                Ow[((size_t)(b * S_ + s)) * HID + h * HD + d] = (bf16_t)(oa[mt][nt][j] * inv);
            }
        }
}

// ---------------------------------------------------------------------------
// Scratch overlay inside d_out (all regions phase-disjoint):
//   O1 = out[0 : 8388608)          : wqb/wkb/wvb bf16 -> final out (gemm1)
//   O2 = out[8388608 : 16777216)   : qb bf16 | wob bf16 -> final key (bcast)
//   O3 = out[16777216 : 25165824)  : hsb bf16, then o_ws (alias) -> final value (bcast)
// d_ws: k_ws/v_ws/vt_ws bf16 = 3 MB only.
// Order: convert -> gemm0 -> attn -> gemm1 -> broadcast_kv (last).
// ---------------------------------------------------------------------------
extern "C" void kernel_launch(void* const* d_in, const int* in_sizes, int n_in,
                              void* d_out, int out_size, void* d_ws, size_t ws_size,
                              hipStream_t stream) {
    const float* hs   = (const float*)d_in[0];
    const float* mask = (const float*)d_in[1];
    const float* Wq   = (const float*)d_in[2];
    const float* Wk   = (const float*)d_in[3];
    const float* Wv   = (const float*)d_in[4];
    const float* Wo   = (const float*)d_in[5];
    float* out = (float*)d_out;

    bf16_t* wqb = (bf16_t*)out;                         // O1
    bf16_t* wkb = wqb + 4194304;
    bf16_t* wvb = wkb + 262144;
    bf16_t* qb  = (bf16_t*)(out + 8388608);             // O2
    bf16_t* wob = (bf16_t*)(out + 12582912);            // O2 tail
    bf16_t* hsb = (bf16_t*)(out + 16777216);            // O3
    bf16_t* o_ws = hsb;                                 // alias (hsb dead after gemm0)

    bf16_t* k_ws  = (bf16_t*)d_ws;                      // 524,288 bf16
    bf16_t* v_ws  = k_ws + 524288;
    bf16_t* vt_ws = v_ws + 524288;                      // total 3 MB

    // 1) fp32 -> bf16 staging
    convert_bf16<<<2048, 256, 0, stream>>>(hs, Wq, Wk, Wv, Wo, hsb, wqb, wkb, wvb, wob);
    // 2) QKV projection: Q->qb (O2), K->k_ws, V->v_ws + vt_ws
    gemm_nt<0><<<dim3(18, 32), 256, 0, stream>>>(hsb, wqb, wkb, wvb, qb, k_ws, v_ws, vt_ws, nullptr);
    // 3) flash MQA attention -> o_ws (O3, overwrites dead hsb)
    attn_kernel<<<dim3(16, 32), 256, 0, stream>>>(qb, k_ws, vt_ws, mask, o_ws);
    // 4) output projection -> fp32 out (O1, overwrites dead wq/wk/wv)
    gemm_nt<1><<<dim3(16, 32), 256, 0, stream>>>(o_ws, wob, nullptr, nullptr, nullptr, nullptr, nullptr, nullptr, out);
    // 5) key/value broadcast -> O2/O3 (overwrites dead qb/wob/o_ws)
    broadcast_kv<<<4096, 256, 0, stream>>>(k_ws, v_ws, out + 8388608, out + 16777216);
}

// Round 9
// 381.084 us; speedup vs baseline: 1.3310x; 1.3310x over previous
//
#include <hip/hip_runtime.h>
#include <hip/hip_bf16.h>
#include <math.h>

#define B_   2
#define S_   2048
#define HID  2048
#define NH   16
#define HD   128

typedef __bf16 bf16_t;
typedef __bf16 bf16x4 __attribute__((ext_vector_type(4)));
typedef __bf16 bf16x8 __attribute__((ext_vector_type(8)));
typedef float  f32x4  __attribute__((ext_vector_type(4)));
typedef unsigned int u32x4 __attribute__((ext_vector_type(4)));

__device__ __forceinline__ f32x4 mfma16(bf16x8 a, bf16x8 b, f32x4 c) {
    return __builtin_amdgcn_mfma_f32_16x16x32_bf16(a, b, c, 0, 0, 0);
}

__device__ __forceinline__ void gl2lds16(const void* g, void* l) {
    __builtin_amdgcn_global_load_lds((__attribute__((address_space(1))) void*)(g),
                                     (__attribute__((address_space(3))) void*)(l),
                                     16, 0, 0);
}

// pack two floats into one u32 of 2 bf16 (lo = a, hi = b)
__device__ __forceinline__ unsigned int pkbf(float a, float b) {
    unsigned short ua = __builtin_bit_cast(unsigned short, (bf16_t)a);
    unsigned short ub = __builtin_bit_cast(unsigned short, (bf16_t)b);
    return (unsigned int)ua | ((unsigned int)ub << 16);
}

// ---------------------------------------------------------------------------
// fp32 -> bf16 conversion of hs + 4 weights (float4 in, bf16x4 out).
// ---------------------------------------------------------------------------
__global__ void convert_bf16(const float* __restrict__ s0, const float* __restrict__ s1,
                             const float* __restrict__ s2, const float* __restrict__ s3,
                             const float* __restrict__ s4,
                             bf16_t* __restrict__ d0, bf16_t* __restrict__ d1,
                             bf16_t* __restrict__ d2, bf16_t* __restrict__ d3,
                             bf16_t* __restrict__ d4)
{
    const size_t stride = (size_t)gridDim.x * blockDim.x;
    for (size_t i = (size_t)blockIdx.x * blockDim.x + threadIdx.x; i < 4325376; i += stride) {
        const float* s; bf16_t* d; size_t off;
        if (i < 2097152)      { s = s0; d = d0; off = i; }
        else if (i < 3145728) { s = s1; d = d1; off = i - 2097152; }
        else if (i < 3211264) { s = s2; d = d2; off = i - 3145728; }
        else if (i < 3276800) { s = s3; d = d3; off = i - 3211264; }
        else                  { s = s4; d = d4; off = i - 3276800; }
        float4 v = ((const float4*)s)[off];
        bf16x4 o;
        o[0] = (bf16_t)v.x; o[1] = (bf16_t)v.y; o[2] = (bf16_t)v.z; o[3] = (bf16_t)v.w;
        ((bf16x4*)d)[off] = o;
    }
}

// ---------------------------------------------------------------------------
// broadcast compact bf16 K/V [b][s][128] -> fp32 key/value_states [b][16][s][128].
// ---------------------------------------------------------------------------
__global__ void broadcast_kv(const bf16_t* __restrict__ k_ws, const bf16_t* __restrict__ v_ws,
                             float* __restrict__ keyo, float* __restrict__ valo)
{
    const size_t stride = (size_t)gridDim.x * blockDim.x;
    for (size_t i = (size_t)blockIdx.x * blockDim.x + threadIdx.x; i < 4194304; i += stride) {
        int which = i >= 2097152;
        size_t f = which ? i - 2097152 : i;
        size_t e = f * 4;                         // < 8388608
        int d = (int)(e & 127);
        size_t s = (e >> 7) & 2047;
        size_t b = e >> 22;                       // 0 or 1
        const bf16_t* src = (which ? v_ws : k_ws) + (b * S_ + s) * HD + d;
        bf16x4 kv = *(const bf16x4*)src;
        float4 o;
        o.x = (float)kv[0]; o.y = (float)kv[1]; o.z = (float)kv[2]; o.w = (float)kv[3];
        *(float4*)((which ? valo : keyo) + e) = o;
    }
}

// ---------------------------------------------------------------------------
// NT GEMM, 128x128 tile, BK=32, 4 waves (2x2 of 64x64), mfma 16x16x32 bf16.
// MODE 0: C = Xb @ [Wq;Wk;Wv]b^T (N=2304): bn<16 -> qb; bn==16 -> k_ws;
//         bn==17 -> v_ws + vt_ws.   MODE 1: C = O @ Wo^T -> fp32 out.
// ---------------------------------------------------------------------------
template <int MODE>
__global__ __launch_bounds__(256, 2)
void gemm_nt(const bf16_t* __restrict__ A,  const bf16_t* __restrict__ B0,
             const bf16_t* __restrict__ B1, const bf16_t* __restrict__ B2,
             bf16_t* __restrict__ q_ws, bf16_t* __restrict__ k_ws,
             bf16_t* __restrict__ v_ws, bf16_t* __restrict__ vt_ws,
             float* __restrict__ outf)
{
    __shared__ __align__(16) ushort sA[128 * 32];
    __shared__ __align__(16) ushort sB[128 * 32];

    const int tid  = threadIdx.x;
    const int lane = tid & 63;
    const int wave = tid >> 6;
    const int quad = lane >> 4;
    const int l16  = lane & 15;
    const int bn = blockIdx.x, bm = blockIdx.y;
    const int wm = (wave & 1) * 64;
    const int wn = (wave >> 1) * 64;

    const bf16_t* Bbase;
    if (MODE == 0) Bbase = (bn < 16) ? (B0 + (size_t)bn * 128 * HID) : (bn == 16 ? B1 : B2);
    else           Bbase = B0 + (size_t)bn * 128 * HID;
    const bf16_t* Abase = A + (size_t)bm * 128 * HID;

    const int c0 = tid, c1 = tid + 256;
    const int r0 = c0 >> 2, o0 = (c0 & 3) * 8;
    const int r1 = c1 >> 2, o1 = (c1 & 3) * 8;

    f32x4 acc[4][4] = {};

    for (int kt = 0; kt < HID / 32; ++kt) {
        const int ko = kt * 32;
        gl2lds16(Abase + (size_t)r0 * HID + ko + o0, sA + c0 * 8);
        gl2lds16(Abase + (size_t)r1 * HID + ko + o1, sA + c1 * 8);
        gl2lds16(Bbase + (size_t)r0 * HID + ko + o0, sB + c0 * 8);
        gl2lds16(Bbase + (size_t)r1 * HID + ko + o1, sB + c1 * 8);
        __syncthreads();

        bf16x8 af[4], bfr[4];
        for (int mt = 0; mt < 4; ++mt)
            af[mt] = *(const bf16x8*)(sA + (wm + mt * 16 + l16) * 32 + quad * 8);
        for (int nt = 0; nt < 4; ++nt)
            bfr[nt] = *(const bf16x8*)(sB + (wn + nt * 16 + l16) * 32 + quad * 8);
        for (int mt = 0; mt < 4; ++mt)
            for (int nt = 0; nt < 4; ++nt)
                acc[mt][nt] = mfma16(af[mt], bfr[nt], acc[mt][nt]);
        __syncthreads();
    }

    for (int mt = 0; mt < 4; ++mt) {
        for (int nt = 0; nt < 4; ++nt) {
            for (int j = 0; j < 4; ++j) {
                float v = acc[mt][nt][j];
                int row = bm * 128 + wm + mt * 16 + quad * 4 + j;
                int col = wn + nt * 16 + l16;
                if (MODE == 1) {
                    outf[(size_t)row * HID + bn * 128 + col] = v;
                } else {
                    bf16_t bv = (bf16_t)v;
                    if (bn < 16) {
                        q_ws[(size_t)row * HID + bn * 128 + col] = bv;
                    } else {
                        int b = row >> 11, s = row & 2047, d = col;
                        if (bn == 16) {
                            k_ws[((size_t)b * S_ + s) * HD + d] = bv;
                        } else {
                            v_ws[((size_t)b * S_ + s) * HD + d] = bv;
                            vt_ws[((size_t)b * HD + d) * S_ + s] = bv;
                        }
                    }
                }
            }
        }
    }
}

// ---------------------------------------------------------------------------
// Flash-style MQA attention, round 7 (2nd resubmit): ASYNC DOUBLE-BUFFERED
// STAGING (T3 minimum 2-phase). The 2-phase stall (stage -> wait -> barrier
// -> compute) was the invariant ~90% bubble across r0-r5. Fix: per iter,
// issue next tile's K/V via global_load_lds DMA into buf^1 (zero VGPR),
// compute current tile from buf, then ONE __syncthreads (the compiler's
// vmcnt drain now waits on loads that had the whole compute phase to land).
// XOR swizzle moved to the gl2lds SOURCE address (rule 21: linear dest +
// inverse-swz source + swz read). Mask-adds precomputed once into LDS.
// In-register softmax + P routing from r5 (twice verified). Block 256 thr
// (4 waves x 32 q-rows), grid (16,32), LDS 72.5 KB -> 2 blocks/CU.
// ---------------------------------------------------------------------------
#define KBUF0 0        // ushort offsets
#define VBUF0 8192
#define KBUF1 16384
#define VBUF1 24576
#define MADD  32768    // f32 maskadd[2048] = 4096 ushorts; total 36864 u = 72.5 KB

__global__ __launch_bounds__(256, 2)
void attn_kernel(const bf16_t* __restrict__ Qw, const bf16_t* __restrict__ Kc,
                 const bf16_t* __restrict__ Vt, const float* __restrict__ mask,
                 bf16_t* __restrict__ Ow)
{
    __shared__ __align__(16) ushort smem[36864];
    float* sMadd = (float*)&smem[MADD];

    const int tid  = threadIdx.x;
    const int lane = tid & 63;
    const int wave = tid >> 6;     // 0..3
    const int quad = lane >> 4;
    const int l16  = lane & 15;
    const int qt = blockIdx.x;     // 0..15 (128-row q-tiles)
    const int bh = blockIdx.y;     // 0..31
    const int b = bh >> 4, h = bh & 15;

    const bf16_t* kg = Kc + (size_t)b * S_ * HD;
    const bf16_t* vg = Vt + (size_t)b * HD * S_;
    const float*  mg = mask + (size_t)b * S_;

    // ---- async stage of K/V tile t into (kofs,vofs); source pre-swizzled ----
    auto STAGE = [&](int t, int kofs, int vofs) {
        const bf16_t* kb = kg + (size_t)t * 64 * HD;
        const bf16_t* vb = vg + t * 64;
#pragma unroll
        for (int i = 0; i < 4; ++i) {
            int c = tid + i * 256;                       // 0..1023
            int kr = c >> 4, kc = c & 15;                // K: [64][128] linear dest
            gl2lds16(kb + (size_t)kr * HD + ((kc ^ (kr & 7)) << 3),
                     &smem[kofs + c * 8]);
            int vr = c >> 3, vc = c & 7;                 // V^T: [128][64] linear dest
            gl2lds16(vb + (size_t)vr * S_ + ((vc ^ (vr & 7)) << 3),
                     &smem[vofs + c * 8]);
        }
    };

    // ---- Q fragments (B-operand: row=q=l16, k-elems=d): global -> regs ----
    bf16x8 qf[2][4];
    {
        const bf16_t* qg = Qw + ((size_t)(b * S_ + qt * 128 + wave * 32)) * HID + h * HD;
#pragma unroll
        for (int mt = 0; mt < 2; ++mt)
#pragma unroll
            for (int kk = 0; kk < 4; ++kk)
                qf[mt][kk] = *(const bf16x8*)(qg + (size_t)(mt * 16 + l16) * HID + kk * 32 + quad * 8);
    }

    f32x4 oa[2][8] = {};
    float mrow[2] = { -INFINITY, -INFINITY };
    float lrow[2] = { 0.f, 0.f };

    const float scale2 = 0.08838834764831845f * 1.4426950408889634f;  // /sqrt(128)*log2(e)
    const float NEGF   = -3.4028234663852886e38f;
    const float LOG2E  = 1.4426950408889634f;

    // ---- prologue: maskadd precompute + stage tile 0 ----
#pragma unroll
    for (int i = 0; i < 8; ++i) {
        int idx = tid + i * 256;
        sMadd[idx] = (1.0f - mg[idx]) * NEGF * LOG2E;
    }
    STAGE(0, KBUF0, VBUF0);
    __syncthreads();

    // ---- one k-tile step: stage(t+1,next) async, compute(t,cur), barrier ----
    auto body = [&](int t, int kcur, int vcur, int knxt, int vnxt) {
        if (t + 1 < S_ / 64) STAGE(t + 1, knxt, vnxt);

        // S^T = (K Q^T): sa[mt][nt]: row=k_local(quad*4+j), col=q(l16)
        f32x4 sa[2][4] = {};
#pragma unroll
        for (int kk = 0; kk < 4; ++kk)
#pragma unroll
            for (int nt = 0; nt < 4; ++nt) {
                bf16x8 kf = *(const bf16x8*)(&smem[kcur + (nt * 16 + l16) * 128 + (((4 * kk + quad) ^ (l16 & 7)) << 3)]);
#pragma unroll
                for (int mt = 0; mt < 2; ++mt)
                    sa[mt][nt] = mfma16(kf, qf[mt][kk], sa[mt][nt]);
            }
        // scale + precomputed mask-add (indexed by k = nt*16 + quad*4 + j)
#pragma unroll
        for (int nt = 0; nt < 4; ++nt) {
            f32x4 m4 = *(const f32x4*)&sMadd[t * 64 + nt * 16 + quad * 4];
#pragma unroll
            for (int mt = 0; mt < 2; ++mt)
#pragma unroll
                for (int j = 0; j < 4; ++j)
                    sa[mt][nt][j] = sa[mt][nt][j] * scale2 + m4[j];
        }

        // in-register online softmax: lane owns q=l16 (16 k-vals in-lane)
        float rm[2];
#pragma unroll
        for (int mt = 0; mt < 2; ++mt) {
            float m = sa[mt][0][0];
#pragma unroll
            for (int nt = 0; nt < 4; ++nt)
#pragma unroll
                for (int j = 0; j < 4; ++j)
                    m = fmaxf(m, sa[mt][nt][j]);
            m = fmaxf(m, __shfl_xor(m, 16));
            m = fmaxf(m, __shfl_xor(m, 32));
            rm[mt] = m;
        }
        bool need = (rm[0] > mrow[0] + 8.0f) || (rm[1] > mrow[1] + 8.0f);
        if (__any((int)need)) {
#pragma unroll
            for (int mt = 0; mt < 2; ++mt) {
                float mnew  = fmaxf(mrow[mt], rm[mt]);
                float alpha = exp2f(mrow[mt] - mnew);
                mrow[mt] = mnew;
                lrow[mt] *= alpha;
#pragma unroll
                for (int j = 0; j < 4; ++j) {
                    float aj = __shfl(alpha, (lane & 48) | (quad * 4 + j));
#pragma unroll
                    for (int nt = 0; nt < 8; ++nt) oa[mt][nt][j] *= aj;
                }
            }
        }
        // p = exp2(s - m), packed to bf16 pairs; row-sum -> lrow
        unsigned int g[2][4][2];
#pragma unroll
        for (int mt = 0; mt < 2; ++mt) {
            float rs = 0.f;
#pragma unroll
            for (int nt = 0; nt < 4; ++nt) {
                float p0 = exp2f(sa[mt][nt][0] - mrow[mt]);
                float p1 = exp2f(sa[mt][nt][1] - mrow[mt]);
                float p2 = exp2f(sa[mt][nt][2] - mrow[mt]);
                float p3 = exp2f(sa[mt][nt][3] - mrow[mt]);
                rs += (p0 + p1) + (p2 + p3);
                g[mt][nt][0] = pkbf(p0, p1);
                g[mt][nt][1] = pkbf(p2, p3);
            }
            rs += __shfl_xor(rs, 16);
            rs += __shfl_xor(rs, 32);
            lrow[mt] += rs;
        }

        // build PV A-frags by lane-local quad routing (same l16 column)
        bf16x8 pf[2][2];
        {
            const int sl = ((quad & 1) << 5) + l16;   // src for e0..3
            const int sh = sl + 16;                   // src for e4..7
            const bool hi = (quad & 2) != 0;          // nt-select
#pragma unroll
            for (int kk = 0; kk < 2; ++kk)
#pragma unroll
                for (int mt = 0; mt < 2; ++mt) {
                    unsigned int a0 = __shfl(g[mt][2 * kk][0], sl);
                    unsigned int a1 = __shfl(g[mt][2 * kk][1], sl);
                    unsigned int b0 = __shfl(g[mt][2 * kk + 1][0], sl);
                    unsigned int b1 = __shfl(g[mt][2 * kk + 1][1], sl);
                    unsigned int c0 = __shfl(g[mt][2 * kk][0], sh);
                    unsigned int c1 = __shfl(g[mt][2 * kk][1], sh);
                    unsigned int d0 = __shfl(g[mt][2 * kk + 1][0], sh);
                    unsigned int d1 = __shfl(g[mt][2 * kk + 1][1], sh);
                    u32x4 w;
                    w[0] = hi ? b0 : a0;
                    w[1] = hi ? b1 : a1;
                    w[2] = hi ? d0 : c0;
                    w[3] = hi ? d1 : c1;
                    pf[mt][kk] = __builtin_bit_cast(bf16x8, w);
                }
        }

        // O += P V
#pragma unroll
        for (int kk = 0; kk < 2; ++kk)
#pragma unroll
            for (int nt = 0; nt < 8; ++nt) {
                bf16x8 vf = *(const bf16x8*)(&smem[vcur + (nt * 16 + l16) * 64 + (((4 * kk + quad) ^ (l16 & 7)) << 3)]);
#pragma unroll
                for (int mt = 0; mt < 2; ++mt)
                    oa[mt][nt] = mfma16(pf[mt][kk], vf, oa[mt][nt]);
            }

        __syncthreads();   // drains my gl2lds (vmcnt) + everyone's reads of cur
    };

    for (int kt = 0; kt < S_ / 64; kt += 2) {
        body(kt,     KBUF0, VBUF0, KBUF1, VBUF1);
        body(kt + 1, KBUF1, VBUF1, KBUF0, VBUF0);
    }

    // ---- epilogue: O /= l (l at lane l16=row; fetch via shfl), write ----
#pragma unroll
    for (int mt = 0; mt < 2; ++mt)
#pragma unroll
        for (int j = 0; j < 4; ++j) {
            float lv = __shfl(lrow[mt], (lane & 48) | (quad * 4 + j));
            float inv = 1.0f / lv;
            int s = qt * 128 + wave * 32 + mt * 16 + quad * 4 + j;
#pragma unroll
            for (int nt = 0; nt < 8; ++nt) {
                int d = nt * 16 + l16;
                Ow[((size_t)(b * S_ + s)) * HID + h * HD + d] = (bf16_t)(oa[mt][nt][j] * inv);
            }
        }
}

// ---------------------------------------------------------------------------
// Scratch overlay inside d_out (all regions phase-disjoint):
//   O1 = out[0 : 8388608)          : wqb/wkb/wvb bf16 -> final out (gemm1)
//   O2 = out[8388608 : 16777216)   : qb bf16 | wob bf16 -> final key (bcast)
//   O3 = out[16777216 : 25165824)  : hsb bf16, then o_ws (alias) -> final value (bcast)
// d_ws: k_ws/v_ws/vt_ws bf16 = 3 MB only.
// Order: convert -> gemm0 -> attn -> gemm1 -> broadcast_kv (last).
// ---------------------------------------------------------------------------
extern "C" void kernel_launch(void* const* d_in, const int* in_sizes, int n_in,
                              void* d_out, int out_size, void* d_ws, size_t ws_size,
                              hipStream_t stream) {
    const float* hs   = (const float*)d_in[0];
    const float* mask = (const float*)d_in[1];
    const float* Wq   = (const float*)d_in[2];
    const float* Wk   = (const float*)d_in[3];
    const float* Wv   = (const float*)d_in[4];
    const float* Wo   = (const float*)d_in[5];
    float* out = (float*)d_out;

    bf16_t* wqb = (bf16_t*)out;                         // O1
    bf16_t* wkb = wqb + 4194304;
    bf16_t* wvb = wkb + 262144;
    bf16_t* qb  = (bf16_t*)(out + 8388608);             // O2
    bf16_t* wob = (bf16_t*)(out + 12582912);            // O2 tail
    bf16_t* hsb = (bf16_t*)(out + 16777216);            // O3
    bf16_t* o_ws = hsb;                                 // alias (hsb dead after gemm0)

    bf16_t* k_ws  = (bf16_t*)d_ws;                      // 524,288 bf16
    bf16_t* v_ws  = k_ws + 524288;
    bf16_t* vt_ws = v_ws + 524288;                      // total 3 MB

    // 1) fp32 -> bf16 staging
    convert_bf16<<<2048, 256, 0, stream>>>(hs, Wq, Wk, Wv, Wo, hsb, wqb, wkb, wvb, wob);
    // 2) QKV projection: Q->qb (O2), K->k_ws, V->v_ws + vt_ws
    gemm_nt<0><<<dim3(18, 32), 256, 0, stream>>>(hsb, wqb, wkb, wvb, qb, k_ws, v_ws, vt_ws, nullptr);
    // 3) flash MQA attention -> o_ws (O3, overwrites dead hsb)
    attn_kernel<<<dim3(16, 32), 256, 0, stream>>>(qb, k_ws, vt_ws, mask, o_ws);
    // 4) output projection -> fp32 out (O1, overwrites dead wq/wk/wv)
    gemm_nt<1><<<dim3(16, 32), 256, 0, stream>>>(o_ws, wob, nullptr, nullptr, nullptr, nullptr, nullptr, nullptr, out);
    // 5) key/value broadcast -> O2/O3 (overwrites dead qb/wob/o_ws)
    broadcast_kv<<<4096, 256, 0, stream>>>(k_ws, v_ws, out + 8388608, out + 16777216);
}